// Round 2
// baseline (995.480 us; speedup 1.0000x reference)
//
#include <hip/hip_runtime.h>
#include <hip/hip_bf16.h>

#define S_LEN 2048
#define D_DIM 128
#define BH_N  64
#define BR    64
#define BC    64
#define NTILE (S_LEN / BC)
#define SCALE 0.08838834764831845f

typedef __attribute__((ext_vector_type(8)))  short short8;
typedef __attribute__((ext_vector_type(16))) float f32x16;

__device__ __forceinline__ ushort f2bf(float f) {
  union { float f; unsigned u; } x; x.f = f;
  unsigned r = x.u + 0x7FFFu + ((x.u >> 16) & 1u);
  return (ushort)(r >> 16);
}

__device__ __forceinline__ short8 pack8(float4 a, float4 b) {
  short8 p;
  p[0] = (short)f2bf(a.x); p[1] = (short)f2bf(a.y);
  p[2] = (short)f2bf(a.z); p[3] = (short)f2bf(a.w);
  p[4] = (short)f2bf(b.x); p[5] = (short)f2bf(b.y);
  p[6] = (short)f2bf(b.z); p[7] = (short)f2bf(b.w);
  return p;
}

// ============================ Kernel A: flash ctx + l ========================
// Per block: 64 q-rows of one (b,h). 4 waves: wq=w>>1 picks 32 q-rows,
// wk=w&1 picks 32 k-cols (S phase) / 64 d-cols (PV phase).
// mfma_f32_32x32x16_bf16: C/D col=lane&31, row=(r&3)+8*(r>>2)+4*(lane>>5);
// A row=lane&31 k=8*(lane>>5)+e; B col=lane&31 k=8*(lane>>5)+e.
__global__ __launch_bounds__(256, 2) void attn_flash_kernel(
    const float* __restrict__ q, const float* __restrict__ k,
    const float* __restrict__ v, float* __restrict__ ctx,
    float* __restrict__ lsum_out) {
  __shared__ __align__(16) char klds[BC * 256];      // 64 x 128 bf16, swizzled
  __shared__ __align__(16) char vtlds[D_DIM * 128];  // 128(d) x 64(k) bf16, swizzled
  __shared__ __align__(16) char plds[BR * 128];      // 64(q) x 64(k) bf16, swizzled
  __shared__ float lred[2][BR];

  const int tid  = threadIdx.x;
  const int lane = tid & 63;
  const int w    = tid >> 6;
  const int wq   = w >> 1, wk = w & 1;
  const int l31  = lane & 31, lhi = lane >> 5;

  const int bid = blockIdx.x;
  const int qb  = (NTILE - 1) - (bid >> 6);   // big blocks first
  const int bh  = bid & 63;

  const float* qbase = q + (size_t)bh * S_LEN * D_DIM;
  const float* kbase = k + (size_t)bh * S_LEN * D_DIM;
  const float* vbase = v + (size_t)bh * S_LEN * D_DIM;

  // ---- Q fragments, registers, reused all iterations ----
  short8 qf[8];
  {
    const float* qrow = qbase + (size_t)(qb * BR + wq * 32 + l31) * D_DIM;
    #pragma unroll
    for (int s = 0; s < 8; ++s) {
      int d0 = 16 * s + 8 * lhi;
      float4 a = *(const float4*)(qrow + d0);
      float4 b = *(const float4*)(qrow + d0 + 4);
      qf[s] = pack8(a, b);
    }
  }

  // ---- prefetch registers for K,V tiles ----
  float4 kreg[8], vreg[8];

  auto load_k = [&](int kt) {
    int trow = tid >> 2, tc = tid & 3;
    const float* src = kbase + (size_t)(kt * BC + trow) * D_DIM;
    #pragma unroll
    for (int i = 0; i < 4; ++i) {
      int c0 = tc * 8 + i * 32;
      kreg[2 * i]     = *(const float4*)(src + c0);
      kreg[2 * i + 1] = *(const float4*)(src + c0 + 4);
    }
  };
  auto write_k = [&]() {
    int trow = tid >> 2, tc = tid & 3;
    #pragma unroll
    for (int i = 0; i < 4; ++i) {
      int c0 = tc * 8 + i * 32;
      int off = (trow * 256 + c0 * 2) ^ ((trow & 7) << 4);
      *(short8*)(klds + off) = pack8(kreg[2 * i], kreg[2 * i + 1]);
    }
  };
  // V: thread owns k-row pair (2kp,2kp+1) x 16 d's; writes ushort2 (4B) ->
  // bank = kp ^ ((d&7)<<2): conflict-free (2-way dword aliasing only).
  auto load_v = [&](int kt) {
    int kp = tid & 31, dg = tid >> 5;
    const float* r0 = vbase + (size_t)(kt * BC + 2 * kp) * D_DIM + dg * 16;
    #pragma unroll
    for (int i = 0; i < 4; ++i) {
      vreg[i]     = *(const float4*)(r0 + 4 * i);
      vreg[4 + i] = *(const float4*)(r0 + D_DIM + 4 * i);
    }
  };
  auto write_v = [&]() {
    int kp = tid & 31, dg = tid >> 5;
    #pragma unroll
    for (int j = 0; j < 16; ++j) {
      int d = dg * 16 + j;
      float lo = vreg[j >> 2][j & 3];
      float hi = vreg[4 + (j >> 2)][j & 3];
      unsigned u = (unsigned)f2bf(lo) | ((unsigned)f2bf(hi) << 16);
      int off = (d * 128 + kp * 4) ^ ((d & 7) << 4);
      *(unsigned*)(vtlds + off) = u;
    }
  };

  auto compute_s = [&]() -> f32x16 {
    f32x16 acc;
    #pragma unroll
    for (int i = 0; i < 16; ++i) acc[i] = 0.f;
    int krow = wk * 32 + l31;
    int base = krow * 256;
    int swz  = (krow & 7) << 4;
    #pragma unroll
    for (int s = 0; s < 8; ++s) {
      int off = (base + 32 * s + 16 * lhi) ^ swz;
      short8 kf = *(const short8*)(klds + off);
      acc = __builtin_amdgcn_mfma_f32_32x32x16_bf16(qf[s], kf, acc, 0, 0, 0);
    }
    return acc;
  };

  float l_lane[16];
  f32x16 o0, o1;
  #pragma unroll
  for (int i = 0; i < 16; ++i) { l_lane[i] = 0.f; o0[i] = 0.f; o1[i] = 0.f; }

  load_k(0); load_v(0);

  for (int kt = 0; kt <= qb; ++kt) {
    write_k(); write_v();                 // regs (tile kt) -> LDS
    if (kt < qb) { load_k(kt + 1); load_v(kt + 1); }   // hide under S+PV
    __syncthreads();

    f32x16 acc = compute_s();
    int kcol_l = wk * 32 + l31;
    int kcol = kt * BC + kcol_l;
    bool diag = (kt == qb);
    #pragma unroll
    for (int r = 0; r < 16; ++r) {
      int rl = wq * 32 + (r & 3) + 8 * (r >> 2) + 4 * lhi;
      int qrow = qb * BR + rl;
      float e = (diag && kcol > qrow) ? 0.f : __expf(acc[r] * SCALE);
      l_lane[r] += e;
      int poff = (rl * 128 + kcol_l * 2) ^ ((rl & 7) << 4);
      *(ushort*)(plds + poff) = f2bf(e);
    }
    __syncthreads();

    #pragma unroll
    for (int s = 0; s < 4; ++s) {
      int prow = wq * 32 + l31;
      int paoff = (prow * 128 + (16 * s + 8 * lhi) * 2) ^ ((prow & 7) << 4);
      short8 pa = *(const short8*)(plds + paoff);
      int kko = (16 * s + 8 * lhi) * 2;
      int d0 = wk * 64 + l31;
      int d1 = d0 + 32;
      int off0 = (d0 * 128 + kko) ^ ((d0 & 7) << 4);
      int off1 = (d1 * 128 + kko) ^ ((d1 & 7) << 4);
      short8 vb0 = *(const short8*)(vtlds + off0);
      short8 vb1 = *(const short8*)(vtlds + off1);
      o0 = __builtin_amdgcn_mfma_f32_32x32x16_bf16(pa, vb0, o0, 0, 0, 0);
      o1 = __builtin_amdgcn_mfma_f32_32x32x16_bf16(pa, vb1, o1, 0, 0, 0);
    }
    __syncthreads();                      // PV reads done; next iter may overwrite
  }

  // ---- combine l across lanes/waves ----
  #pragma unroll
  for (int r = 0; r < 16; ++r) {
    float x = l_lane[r];
    x += __shfl_xor(x, 1);  x += __shfl_xor(x, 2);  x += __shfl_xor(x, 4);
    x += __shfl_xor(x, 8);  x += __shfl_xor(x, 16);
    l_lane[r] = x;
  }
  if (l31 == 0) {
    #pragma unroll
    for (int r = 0; r < 16; ++r) {
      int rl = wq * 32 + (r & 3) + 8 * (r >> 2) + 4 * lhi;
      lred[wk][rl] = l_lane[r];
    }
  }
  __syncthreads();

  if (tid < BR)
    lsum_out[(size_t)bh * S_LEN + qb * BR + tid] = lred[0][tid] + lred[1][tid];

  float inv_l[16];
  #pragma unroll
  for (int r = 0; r < 16; ++r) {
    int rl = wq * 32 + (r & 3) + 8 * (r >> 2) + 4 * lhi;
    inv_l[r] = 1.0f / (lred[0][rl] + lred[1][rl]);
  }
  #pragma unroll
  for (int r = 0; r < 16; ++r) {
    int rl = wq * 32 + (r & 3) + 8 * (r >> 2) + 4 * lhi;
    size_t obase = (size_t)(bh * S_LEN + qb * BR + rl) * D_DIM;
    ctx[obase + wk * 64 + l31]      = o0[r] * inv_l[r];
    ctx[obase + wk * 64 + 32 + l31] = o1[r] * inv_l[r];
  }
}

// ====================== Kernel B: attention weights ==========================
// One block per 64(q) x 128(k) output tile. No LDS, no barriers: each wave
// loads Q/K fragments straight from global (LLC-hot), recomputes S with the
// SAME bf16 rounding as kernel A, applies exp * 1/l, streams P. Fully-masked
// tiles only zero-fill.
__global__ __launch_bounds__(256, 4) void attn_wts_kernel(
    const float* __restrict__ q, const float* __restrict__ k,
    const float* __restrict__ lsum, float* __restrict__ wts) {
  const int bid = blockIdx.x;
  const int kt2 = bid & 15;
  const int qb  = (bid >> 4) & 31;
  const int bh  = bid >> 9;

  float* wtile = wts + ((size_t)(bh * S_LEN + qb * BR)) * S_LEN + kt2 * 128;
  const int tid = threadIdx.x;

  if (2 * kt2 >= qb + 1) {               // fully above the diagonal -> zeros
    float4 z; z.x = z.y = z.z = z.w = 0.f;
    #pragma unroll
    for (int rr = 0; rr < 64; rr += 8)
      ((float4*)(wtile + (size_t)(rr + (tid >> 5)) * S_LEN))[tid & 31] = z;
    return;
  }

  const int lane = tid & 63;
  const int w    = tid >> 6;
  const int wq   = w >> 1, wk = w & 1;
  const int l31  = lane & 31, lhi = lane >> 5;

  // Q fragment (rows wq*32 + l31)
  short8 qf[8];
  {
    const float* qrow = q + (size_t)(bh * S_LEN + qb * BR + wq * 32 + l31) * D_DIM;
    #pragma unroll
    for (int s = 0; s < 8; ++s) {
      int d0 = 16 * s + 8 * lhi;
      float4 a = *(const float4*)(qrow + d0);
      float4 b = *(const float4*)(qrow + d0 + 4);
      qf[s] = pack8(a, b);
    }
  }

  float invl[16];
  #pragma unroll
  for (int r = 0; r < 16; ++r) {
    int rl = wq * 32 + (r & 3) + 8 * (r >> 2) + 4 * lhi;
    invl[r] = 1.0f / lsum[(size_t)bh * S_LEN + qb * BR + rl];
  }

  #pragma unroll
  for (int c = 0; c < 2; ++c) {
    const int colg_base = kt2 * 128 + wk * 64 + c * 32;
    const float* krow = k + (size_t)(bh * S_LEN + colg_base + l31) * D_DIM;
    f32x16 acc;
    #pragma unroll
    for (int i = 0; i < 16; ++i) acc[i] = 0.f;
    #pragma unroll
    for (int s = 0; s < 8; ++s) {
      int d0 = 16 * s + 8 * lhi;
      float4 a = *(const float4*)(krow + d0);
      float4 b = *(const float4*)(krow + d0 + 4);
      short8 kf = pack8(a, b);
      acc = __builtin_amdgcn_mfma_f32_32x32x16_bf16(qf[s], kf, acc, 0, 0, 0);
    }
    int colg = colg_base + l31;
    #pragma unroll
    for (int r = 0; r < 16; ++r) {
      int rl = wq * 32 + (r & 3) + 8 * (r >> 2) + 4 * lhi;
      int rowg = qb * BR + rl;
      float p = (colg > rowg) ? 0.f : __expf(acc[r] * SCALE) * invl[r];
      wtile[(size_t)rl * S_LEN + wk * 64 + c * 32 + l31] = p;
    }
  }
}

extern "C" void kernel_launch(void* const* d_in, const int* in_sizes, int n_in,
                              void* d_out, int out_size, void* d_ws, size_t ws_size,
                              hipStream_t stream) {
  const float* q = (const float*)d_in[0];
  const float* k = (const float*)d_in[1];
  const float* v = (const float*)d_in[2];
  float* ctx = (float*)d_out;
  float* wts = ctx + (size_t)BH_N * S_LEN * D_DIM;
  float* lsum = (float*)d_ws;   // 64*2048 floats = 512 KB

  attn_flash_kernel<<<dim3(BH_N * NTILE), dim3(256), 0, stream>>>(q, k, v, ctx, lsum);
  attn_wts_kernel<<<dim3(BH_N * NTILE * (S_LEN / 128)), dim3(256), 0, stream>>>(q, k, lsum, wts);
}

// Round 3
// 569.909 us; speedup vs baseline: 1.7467x; 1.7467x over previous
//
#include <hip/hip_runtime.h>
#include <hip/hip_bf16.h>

#define S_LEN 2048
#define D_DIM 128
#define BH_N  64
#define BR    64
#define BC    64
#define NTILE (S_LEN / BC)
#define SCALE 0.08838834764831845f
#define WB    256   // weights-kernel slab width (cols)

typedef __attribute__((ext_vector_type(8)))  short short8;
typedef __attribute__((ext_vector_type(16))) float f32x16;

__device__ __forceinline__ ushort f2bf(float f) {
  union { float f; unsigned u; } x; x.f = f;
  unsigned r = x.u + 0x7FFFu + ((x.u >> 16) & 1u);
  return (ushort)(r >> 16);
}

__device__ __forceinline__ short8 pack8(float4 a, float4 b) {
  short8 p;
  p[0] = (short)f2bf(a.x); p[1] = (short)f2bf(a.y);
  p[2] = (short)f2bf(a.z); p[3] = (short)f2bf(a.w);
  p[4] = (short)f2bf(b.x); p[5] = (short)f2bf(b.y);
  p[6] = (short)f2bf(b.z); p[7] = (short)f2bf(b.w);
  return p;
}

// ============================ Kernel A: flash ctx + l ========================
// (unchanged from R2 — measured ~150 us)
__global__ __launch_bounds__(256, 2) void attn_flash_kernel(
    const float* __restrict__ q, const float* __restrict__ k,
    const float* __restrict__ v, float* __restrict__ ctx,
    float* __restrict__ lsum_out) {
  __shared__ __align__(16) char klds[BC * 256];
  __shared__ __align__(16) char vtlds[D_DIM * 128];
  __shared__ __align__(16) char plds[BR * 128];
  __shared__ float lred[2][BR];

  const int tid  = threadIdx.x;
  const int lane = tid & 63;
  const int w    = tid >> 6;
  const int wq   = w >> 1, wk = w & 1;
  const int l31  = lane & 31, lhi = lane >> 5;

  const int bid = blockIdx.x;
  const int qb  = (NTILE - 1) - (bid >> 6);
  const int bh  = bid & 63;

  const float* qbase = q + (size_t)bh * S_LEN * D_DIM;
  const float* kbase = k + (size_t)bh * S_LEN * D_DIM;
  const float* vbase = v + (size_t)bh * S_LEN * D_DIM;

  short8 qf[8];
  {
    const float* qrow = qbase + (size_t)(qb * BR + wq * 32 + l31) * D_DIM;
    #pragma unroll
    for (int s = 0; s < 8; ++s) {
      int d0 = 16 * s + 8 * lhi;
      float4 a = *(const float4*)(qrow + d0);
      float4 b = *(const float4*)(qrow + d0 + 4);
      qf[s] = pack8(a, b);
    }
  }

  float4 kreg[8], vreg[8];

  auto load_k = [&](int kt) {
    int trow = tid >> 2, tc = tid & 3;
    const float* src = kbase + (size_t)(kt * BC + trow) * D_DIM;
    #pragma unroll
    for (int i = 0; i < 4; ++i) {
      int c0 = tc * 8 + i * 32;
      kreg[2 * i]     = *(const float4*)(src + c0);
      kreg[2 * i + 1] = *(const float4*)(src + c0 + 4);
    }
  };
  auto write_k = [&]() {
    int trow = tid >> 2, tc = tid & 3;
    #pragma unroll
    for (int i = 0; i < 4; ++i) {
      int c0 = tc * 8 + i * 32;
      int off = (trow * 256 + c0 * 2) ^ ((trow & 7) << 4);
      *(short8*)(klds + off) = pack8(kreg[2 * i], kreg[2 * i + 1]);
    }
  };
  auto load_v = [&](int kt) {
    int kp = tid & 31, dg = tid >> 5;
    const float* r0 = vbase + (size_t)(kt * BC + 2 * kp) * D_DIM + dg * 16;
    #pragma unroll
    for (int i = 0; i < 4; ++i) {
      vreg[i]     = *(const float4*)(r0 + 4 * i);
      vreg[4 + i] = *(const float4*)(r0 + D_DIM + 4 * i);
    }
  };
  auto write_v = [&]() {
    int kp = tid & 31, dg = tid >> 5;
    #pragma unroll
    for (int j = 0; j < 16; ++j) {
      int d = dg * 16 + j;
      float lo = vreg[j >> 2][j & 3];
      float hi = vreg[4 + (j >> 2)][j & 3];
      unsigned u = (unsigned)f2bf(lo) | ((unsigned)f2bf(hi) << 16);
      int off = (d * 128 + kp * 4) ^ ((d & 7) << 4);
      *(unsigned*)(vtlds + off) = u;
    }
  };

  auto compute_s = [&]() -> f32x16 {
    f32x16 acc;
    #pragma unroll
    for (int i = 0; i < 16; ++i) acc[i] = 0.f;
    int krow = wk * 32 + l31;
    int base = krow * 256;
    int swz  = (krow & 7) << 4;
    #pragma unroll
    for (int s = 0; s < 8; ++s) {
      int off = (base + 32 * s + 16 * lhi) ^ swz;
      short8 kf = *(const short8*)(klds + off);
      acc = __builtin_amdgcn_mfma_f32_32x32x16_bf16(qf[s], kf, acc, 0, 0, 0);
    }
    return acc;
  };

  float l_lane[16];
  f32x16 o0, o1;
  #pragma unroll
  for (int i = 0; i < 16; ++i) { l_lane[i] = 0.f; o0[i] = 0.f; o1[i] = 0.f; }

  load_k(0); load_v(0);

  for (int kt = 0; kt <= qb; ++kt) {
    write_k(); write_v();
    if (kt < qb) { load_k(kt + 1); load_v(kt + 1); }
    __syncthreads();

    f32x16 acc = compute_s();
    int kcol_l = wk * 32 + l31;
    int kcol = kt * BC + kcol_l;
    bool diag = (kt == qb);
    #pragma unroll
    for (int r = 0; r < 16; ++r) {
      int rl = wq * 32 + (r & 3) + 8 * (r >> 2) + 4 * lhi;
      int qrow = qb * BR + rl;
      float e = (diag && kcol > qrow) ? 0.f : __expf(acc[r] * SCALE);
      l_lane[r] += e;
      int poff = (rl * 128 + kcol_l * 2) ^ ((rl & 7) << 4);
      *(ushort*)(plds + poff) = f2bf(e);
    }
    __syncthreads();

    #pragma unroll
    for (int s = 0; s < 4; ++s) {
      int prow = wq * 32 + l31;
      int paoff = (prow * 128 + (16 * s + 8 * lhi) * 2) ^ ((prow & 7) << 4);
      short8 pa = *(const short8*)(plds + paoff);
      int kko = (16 * s + 8 * lhi) * 2;
      int d0 = wk * 64 + l31;
      int d1 = d0 + 32;
      int off0 = (d0 * 128 + kko) ^ ((d0 & 7) << 4);
      int off1 = (d1 * 128 + kko) ^ ((d1 & 7) << 4);
      short8 vb0 = *(const short8*)(vtlds + off0);
      short8 vb1 = *(const short8*)(vtlds + off1);
      o0 = __builtin_amdgcn_mfma_f32_32x32x16_bf16(pa, vb0, o0, 0, 0, 0);
      o1 = __builtin_amdgcn_mfma_f32_32x32x16_bf16(pa, vb1, o1, 0, 0, 0);
    }
    __syncthreads();
  }

  #pragma unroll
  for (int r = 0; r < 16; ++r) {
    float x = l_lane[r];
    x += __shfl_xor(x, 1);  x += __shfl_xor(x, 2);  x += __shfl_xor(x, 4);
    x += __shfl_xor(x, 8);  x += __shfl_xor(x, 16);
    l_lane[r] = x;
  }
  if (l31 == 0) {
    #pragma unroll
    for (int r = 0; r < 16; ++r) {
      int rl = wq * 32 + (r & 3) + 8 * (r >> 2) + 4 * lhi;
      lred[wk][rl] = l_lane[r];
    }
  }
  __syncthreads();

  if (tid < BR)
    lsum_out[(size_t)bh * S_LEN + qb * BR + tid] = lred[0][tid] + lred[1][tid];

  float inv_l[16];
  #pragma unroll
  for (int r = 0; r < 16; ++r) {
    int rl = wq * 32 + (r & 3) + 8 * (r >> 2) + 4 * lhi;
    inv_l[r] = 1.0f / (lred[0][rl] + lred[1][rl]);
  }
  #pragma unroll
  for (int r = 0; r < 16; ++r) {
    int rl = wq * 32 + (r & 3) + 8 * (r >> 2) + 4 * lhi;
    size_t obase = (size_t)(bh * S_LEN + qb * BR + rl) * D_DIM;
    ctx[obase + wk * 64 + l31]      = o0[r] * inv_l[r];
    ctx[obase + wk * 64 + 32 + l31] = o1[r] * inv_l[r];
  }
}

// ====================== Kernel B v2: streaming weights =======================
// One block = 64 q-rows x FULL 2048 cols. Per 256-col slab: MFMA S-slab ->
// exp * (1/l) -> stage fp32 in LDS -> drain with 64-lane float4 row writes
// (1 KB contiguous per store instruction). Masked slabs stream zeros directly.
__global__ __launch_bounds__(256, 2) void attn_wts2_kernel(
    const float* __restrict__ q, const float* __restrict__ k,
    const float* __restrict__ lsum, float* __restrict__ wts) {
  __shared__ __align__(16) float pslab[64 * WB];   // 64 KB

  const int tid  = threadIdx.x;
  const int lane = tid & 63;
  const int w    = tid >> 6;
  const int wq   = w >> 1, wk = w & 1;
  const int l31  = lane & 31, lhi = lane >> 5;

  const int bid   = blockIdx.x;
  const int bh    = bid & 63;
  const int panel = (NTILE - 1) - (bid >> 6);    // big panels first

  float* wtile = wts + ((size_t)(bh * S_LEN + panel * BR)) * S_LEN;
  const int nslab = panel / 4 + 1;               // slabs with any unmasked col
  const int rowmax = panel * BR + BR - 1;

  // Q fragments: rows panel*64 + wq*32 + l31 — loaded ONCE per block
  short8 qf[8];
  {
    const float* qrow = q + (size_t)(bh * S_LEN + panel * BR + wq * 32 + l31) * D_DIM;
    #pragma unroll
    for (int s = 0; s < 8; ++s) {
      int d0 = 16 * s + 8 * lhi;
      float4 a = *(const float4*)(qrow + d0);
      float4 b = *(const float4*)(qrow + d0 + 4);
      qf[s] = pack8(a, b);
    }
  }

  float invl[16];
  #pragma unroll
  for (int r = 0; r < 16; ++r) {
    int rl = wq * 32 + (r & 3) + 8 * (r >> 2) + 4 * lhi;
    invl[r] = 1.0f / lsum[(size_t)bh * S_LEN + panel * BR + rl];
  }

  const float* kbase = k + (size_t)bh * S_LEN * D_DIM;

  for (int s = 0; s < nslab; ++s) {
    // ---- compute 4 col-blocks of 32 into LDS ----
    #pragma unroll
    for (int cb = 0; cb < 4; ++cb) {
      const int colb = s * WB + wk * 128 + cb * 32;   // global col base
      const int col_local = wk * 128 + cb * 32 + l31;
      if (colb > rowmax) {                            // fully masked block
        #pragma unroll
        for (int r = 0; r < 16; ++r) {
          int rl = wq * 32 + (r & 3) + 8 * (r >> 2) + 4 * lhi;
          pslab[rl * WB + col_local] = 0.f;
        }
        continue;
      }
      const float* krow = kbase + (size_t)(colb + l31) * D_DIM;
      f32x16 acc;
      #pragma unroll
      for (int i = 0; i < 16; ++i) acc[i] = 0.f;
      #pragma unroll
      for (int s8 = 0; s8 < 8; ++s8) {
        int d0 = 16 * s8 + 8 * lhi;
        float4 a = *(const float4*)(krow + d0);
        float4 b = *(const float4*)(krow + d0 + 4);
        short8 kf = pack8(a, b);
        acc = __builtin_amdgcn_mfma_f32_32x32x16_bf16(qf[s8], kf, acc, 0, 0, 0);
      }
      const int cg = colb + l31;
      #pragma unroll
      for (int r = 0; r < 16; ++r) {
        int rl = wq * 32 + (r & 3) + 8 * (r >> 2) + 4 * lhi;
        int rowg = panel * BR + rl;
        float p = (cg > rowg) ? 0.f : __expf(acc[r] * SCALE) * invl[r];
        pslab[rl * WB + col_local] = p;
      }
    }
    __syncthreads();
    // ---- drain: each wave writes one full 1 KB row-chunk per pass ----
    #pragma unroll
    for (int pass = 0; pass < 16; ++pass) {
      int row = pass * 4 + w;
      float4 val = *(const float4*)&pslab[row * WB + lane * 4];
      *(float4*)(wtile + (size_t)row * S_LEN + s * WB + lane * 4) = val;
    }
    __syncthreads();
  }

  // ---- zero slabs (fully above diagonal): stream zeros, 1 KB/wave/pass ----
  float4 z; z.x = z.y = z.z = z.w = 0.f;
  for (int s = nslab; s < S_LEN / WB; ++s) {
    #pragma unroll
    for (int pass = 0; pass < 16; ++pass) {
      int row = pass * 4 + w;
      *(float4*)(wtile + (size_t)row * S_LEN + s * WB + lane * 4) = z;
    }
  }
}

extern "C" void kernel_launch(void* const* d_in, const int* in_sizes, int n_in,
                              void* d_out, int out_size, void* d_ws, size_t ws_size,
                              hipStream_t stream) {
  const float* q = (const float*)d_in[0];
  const float* k = (const float*)d_in[1];
  const float* v = (const float*)d_in[2];
  float* ctx = (float*)d_out;
  float* wts = ctx + (size_t)BH_N * S_LEN * D_DIM;
  float* lsum = (float*)d_ws;   // 64*2048 floats = 512 KB

  attn_flash_kernel<<<dim3(BH_N * NTILE), dim3(256), 0, stream>>>(q, k, v, ctx, lsum);
  attn_wts2_kernel<<<dim3(BH_N * NTILE), dim3(256), 0, stream>>>(q, k, lsum, wts);
}